// Round 5
// baseline (3045.804 us; speedup 1.0000x reference)
//
#include <hip/hip_runtime.h>
#include <hip/hip_bf16.h>

#define BB 128
#define TT 256
#define VV 128
#define HH 1024
#define NG 4096   // 4*H gate columns (permuted: n = hc*4 + kg)
#define KK 1152   // V + H fused reduction dim

typedef unsigned short ushort_t;
typedef short bf16x8 __attribute__((ext_vector_type(8)));
typedef float f32x4 __attribute__((ext_vector_type(4)));

__device__ __forceinline__ ushort_t f2bf(float f) {
  unsigned u = __builtin_bit_cast(unsigned, f);
  u += 0x7fffu + ((u >> 16) & 1u);   // RTNE
  return (ushort_t)(u >> 16);
}

__device__ __forceinline__ uint4 pack8(const float* p) {
  float4 a = *(const float4*)p;
  float4 b = *(const float4*)(p + 4);
  uint4 r;
  r.x = (unsigned)f2bf(a.x) | ((unsigned)f2bf(a.y) << 16);
  r.y = (unsigned)f2bf(a.z) | ((unsigned)f2bf(a.w) << 16);
  r.z = (unsigned)f2bf(b.x) | ((unsigned)f2bf(b.y) << 16);
  r.w = (unsigned)f2bf(b.z) | ((unsigned)f2bf(b.w) << 16);
  return r;
}

__device__ __forceinline__ f32x4 MFMA(bf16x8 a, bf16x8 b, f32x4 c) {
  return __builtin_amdgcn_mfma_f32_16x16x32_bf16(a, b, c, 0, 0, 0);
}

// fast sigmoid: native v_exp + division (compiler: rcp + NR)
__device__ __forceinline__ float fsig(float x) {
  return 1.f / (1.f + __expf(-x));
}

// ---------------- init: h0 bf16, Wl->bf16, bias = bx+bh (permuted), bar -----
__global__ void init_misc(const float* __restrict__ h_in, const float* __restrict__ Wl,
                          const float* __restrict__ bx, const float* __restrict__ bh,
                          ushort_t* __restrict__ hbf0, ushort_t* __restrict__ wlbf,
                          float* __restrict__ bias, unsigned* __restrict__ bar) {
  int i = blockIdx.x * blockDim.x + threadIdx.x;   // grid covers 131072 exactly
  hbf0[i] = f2bf(h_in[i]);
  wlbf[i] = f2bf(Wl[i]);
  if (i < NG) {
    int kg = i & 3, hc = i >> 2;
    bias[i] = bx[kg * HH + hc] + bh[kg * HH + hc];
  }
  if (i < 544) bar[i] = 0u;
}

// ---------------- x fp32 -> bf16 once (8 elems/thread) ----------------------
__global__ void xconv(const float* __restrict__ x, ushort_t* __restrict__ xbf) {
  size_t i = (size_t)(blockIdx.x * blockDim.x + threadIdx.x) * 8;
  *(uint4*)(xbf + i) = pack8(x + i);
}

// ------------- build WcombT[n][k] bf16, n = hc*4+kg, k = [x(128) | h(1024)] --
__global__ void build_wcombT(const float* __restrict__ Wx, const float* __restrict__ Wh,
                             ushort_t* __restrict__ wcombT) {
  __shared__ float tile[32][33];
  const int k0 = blockIdx.x * 32, hc0 = blockIdx.y * 32, kg = blockIdx.z;
  const int tid = threadIdx.x;
#pragma unroll
  for (int p = 0; p < 4; ++p) {
    int kk = (tid >> 5) + p * 8, hh = tid & 31;
    int k = k0 + kk, hc = hc0 + hh;
    float v = (k < VV) ? Wx[kg * VV * HH + k * HH + hc]
                       : Wh[kg * HH * HH + (k - VV) * HH + hc];
    tile[kk][hh] = v;
  }
  __syncthreads();
#pragma unroll
  for (int p = 0; p < 4; ++p) {
    int hh = (tid >> 5) + p * 8, kk = tid & 31;
    int n = (hc0 + hh) * 4 + kg;
    wcombT[n * KK + k0 + kk] = f2bf(tile[kk][hh]);
  }
}

// ---------------- persistent LSTM: all 256 timesteps, weights in VGPRs ------
// grid 256 (mb = blk&3 -> 32 batch rows, nb = blk>>2 -> 64 gate cols), 4 waves
// No LDS: A-fragments loaded directly from global (rows are lane-fixed).
__global__ __launch_bounds__(256, 1) void lstm_persist(
    const ushort_t* __restrict__ xbf, const ushort_t* __restrict__ wcombT,
    const float* __restrict__ bias, ushort_t* __restrict__ hping,
    unsigned* __restrict__ outs32, const float* __restrict__ c_in,
    float* __restrict__ hout, float* __restrict__ cout,
    unsigned* __restrict__ bar) {
  const int tid = threadIdx.x;
  const int b0 = (blockIdx.x & 3) * 32;
  const int n0 = (blockIdx.x >> 2) * 64;
  const int grp = blockIdx.x & 7;                  // round-robin -> per-XCD group
  const int wave = tid >> 6, lane = tid & 63;
  const int wm = wave >> 1, wn = wave & 1;
  const int c15 = lane & 15, q = lane >> 4;
  const int kg = lane & 3;
  const bool isg = (kg == 2);
  const int arow = wm * 16 + c15;                  // A-fragment row (0..31)
  const int rbase = b0 + wm * 16 + q * 4;
  const int hu0 = (n0 >> 2) + wn * 8 + (c15 >> 2); // + j*4

  // ---- one-time: B fragments into registers ----
  bf16x8 breg[36][2];
#pragma unroll
  for (int ks = 0; ks < 36; ++ks)
#pragma unroll
    for (int j = 0; j < 2; ++j)
      breg[ks][j] = *(const bf16x8*)(wcombT +
          (size_t)(n0 + wn * 32 + j * 16 + c15) * KK + ks * 32 + q * 8);

  float biasr[2];
#pragma unroll
  for (int j = 0; j < 2; ++j)
    biasr[j] = bias[n0 + wn * 32 + j * 16 + c15];

  float cr[2][4];
#pragma unroll
  for (int j = 0; j < 2; ++j)
#pragma unroll
    for (int r = 0; r < 4; ++r)
      cr[j][r] = c_in[(size_t)(rbase + r) * HH + hu0 + j * 4];

  const ushort_t* xlane = xbf + (size_t)(b0 + arow) * (TT * VV) + q * 8;

  // x fragments for t = 0, and x-part MFMAs for t = 0
  bf16x8 xr[4];
#pragma unroll
  for (int ks = 0; ks < 4; ++ks)
    xr[ks] = *(const bf16x8*)(xlane + ks * 32);

  f32x4 a0e = {0.f,0.f,0.f,0.f}, a0o = {0.f,0.f,0.f,0.f};
  f32x4 a1e = {0.f,0.f,0.f,0.f}, a1o = {0.f,0.f,0.f,0.f};
  a0e = MFMA(xr[0], breg[0][0], a0e);
  a1e = MFMA(xr[0], breg[0][1], a1e);
  a0o = MFMA(xr[1], breg[1][0], a0o);
  a1o = MFMA(xr[1], breg[1][1], a1o);
  a0e = MFMA(xr[2], breg[2][0], a0e);
  a1e = MFMA(xr[2], breg[2][1], a1e);
  a0o = MFMA(xr[3], breg[3][0], a0o);
  a1o = MFMA(xr[3], breg[3][1], a1o);

  for (int t = 0; t < TT; ++t) {
    const ushort_t* hc_ = hping + (size_t)(t & 1) * BB * HH;
    ushort_t* hn_ = hping + (size_t)((t + 1) & 1) * BB * HH;
    const ushort_t* hrow = hc_ + (size_t)(b0 + arow) * HH + q * 8;

    // ---- h-part GEMM: direct global loads (64B-coalesced per 16 lanes) ----
#pragma unroll
    for (int hs = 0; hs < 32; hs += 2) {
      bf16x8 af0 = *(const bf16x8*)(hrow + hs * 32);
      bf16x8 af1 = *(const bf16x8*)(hrow + hs * 32 + 32);
      a0e = MFMA(af0, breg[4 + hs][0], a0e);
      a1e = MFMA(af0, breg[4 + hs][1], a1e);
      a0o = MFMA(af1, breg[5 + hs][0], a0o);
      a1o = MFMA(af1, breg[5 + hs][1], a1o);
    }
    f32x4 g0 = a0e + a0o, g1 = a1e + a1o;

    // ---- prefetch x fragments for t+1 (latency hides under pointwise) ----
    if (t < TT - 1) {
#pragma unroll
      for (int ks = 0; ks < 4; ++ks)
        xr[ks] = *(const bf16x8*)(xlane + (t + 1) * VV + ks * 32);
    }

    // ---- pointwise LSTM in registers (4 gates live in 4-lane groups) ----
    const bool last = (t == TT - 1);
#pragma unroll
    for (int j = 0; j < 2; ++j) {
      f32x4 gj = j ? g1 : g0;
#pragma unroll
      for (int r = 0; r < 4; ++r) {
        float pre = gj[r] + biasr[j];
        float sx = isg ? pre + pre : pre;
        float sg = fsig(sx);
        float a = isg ? sg + sg - 1.f : sg;     // own gate activation
        float fv = __shfl_xor(a, 1);
        float gv = __shfl_xor(a, 2);
        float ov = __shfl_xor(fv, 2);
        float cn = fv * cr[j][r] + a * gv;      // valid on kg==0 lanes
        cr[j][r] = cn;
        float hn = ov * (2.f * fsig(cn + cn) - 1.f);   // ov * tanh(cn)
        unsigned hb = f2bf(hn), ob = f2bf(ov);
        unsigned hbp = (unsigned)__shfl_xor((int)hb, 4);
        unsigned obp = (unsigned)__shfl_xor((int)ob, 4);
        if ((lane & 7) == 0) {                  // kg==0 && even hu pair
          int b = rbase + r, hu = hu0 + j * 4;
          // h: device-coherent write-through (sc0 sc1) - no L2 flush needed
          __hip_atomic_store((unsigned*)(hn_ + (size_t)b * HH + hu),
                             hb | (hbp << 16), __ATOMIC_RELAXED,
                             __HIP_MEMORY_SCOPE_AGENT);
          outs32[(((size_t)b * TT + t) * HH + hu) >> 1] = ob | (obp << 16);
        }
        if (last && kg == 0) {
          int b = rbase + r, hu = hu0 + j * 4;
          hout[(size_t)b * HH + hu] = hn;
          cout[(size_t)b * HH + hu] = cn;
        }
      }
    }

    if (t < TT - 1) {
      // ---- barrier: arrive -> overlap x-MFMAs(t+1) -> single-hop poll ----
      __syncthreads();   // vmcnt(0): all waves' WT h-stores visible at LLC
      if (tid == 0)
        __hip_atomic_fetch_add(bar + 32 * (1 + grp), 1u, __ATOMIC_RELAXED,
                               __HIP_MEMORY_SCOPE_AGENT);
      // x-part MFMAs for t+1 (register-only; overlaps barrier wait)
      a0e = (f32x4){0.f,0.f,0.f,0.f}; a0o = (f32x4){0.f,0.f,0.f,0.f};
      a1e = (f32x4){0.f,0.f,0.f,0.f}; a1o = (f32x4){0.f,0.f,0.f,0.f};
      a0e = MFMA(xr[0], breg[0][0], a0e);
      a1e = MFMA(xr[0], breg[0][1], a1e);
      a0o = MFMA(xr[1], breg[1][0], a0o);
      a1o = MFMA(xr[1], breg[1][1], a1o);
      a0e = MFMA(xr[2], breg[2][0], a0e);
      a1e = MFMA(xr[2], breg[2][1], a1e);
      a0o = MFMA(xr[3], breg[3][0], a0o);
      a1o = MFMA(xr[3], breg[3][1], a1o);
      // wave 0: each lane polls one of 8 sub-counters -> one vmem round trip
      if (tid < 64) {
        const unsigned* ctr = bar + 32 * (1 + (tid & 7));
        unsigned tgt = 32u * (unsigned)(t + 1);
        while (true) {
          unsigned v = __hip_atomic_load(ctr, __ATOMIC_RELAXED,
                                         __HIP_MEMORY_SCOPE_AGENT);
          if (__all(v >= tgt)) break;
          __builtin_amdgcn_s_sleep(1);
        }
        __builtin_amdgcn_fence(__ATOMIC_ACQUIRE, "agent");  // single buffer_inv
      }
      __syncthreads();
    }
  }
}

// ---------------- logits = outs(bf16) @ Wl^T + bl ---------------------------
// grid 512, 256 threads (waves 2x2), WG tile 64(M) x 128(N=V)
__global__ __launch_bounds__(256) void logits_gemm(
    const ushort_t* __restrict__ outs, const ushort_t* __restrict__ wlbf,
    const float* __restrict__ bl, float* __restrict__ out) {
  __shared__ __align__(16) ushort_t Asl[2][64][72];
  __shared__ __align__(16) ushort_t Bsl[2][128][72];
  const int tid = threadIdx.x;
  const int m0 = blockIdx.x * 64;
  const int wave = tid >> 6, lane = tid & 63;
  const int wm = wave >> 1, wn = wave & 1;
  const int ar = tid >> 2, ak = (tid & 3) * 16;
  const int br = tid >> 1, bk = (tid & 1) * 32;

  f32x4 acc[2][4];
#pragma unroll
  for (int i = 0; i < 2; ++i)
#pragma unroll
    for (int j = 0; j < 4; ++j) acc[i][j] = {0.f, 0.f, 0.f, 0.f};

  const ushort_t* pa = outs + (size_t)(m0 + ar) * HH + ak;
  uint4 av0 = *(const uint4*)pa, av1 = *(const uint4*)(pa + 8);
  const ushort_t* pb = wlbf + (size_t)br * HH + bk;
  uint4 bv0 = *(const uint4*)pb, bv1 = *(const uint4*)(pb + 8);
  uint4 bv2 = *(const uint4*)(pb + 16), bv3 = *(const uint4*)(pb + 24);

  int buf = 0;
  for (int s = 0; s < 16; ++s) {
    *(uint4*)&Asl[buf][ar][ak] = av0;
    *(uint4*)&Asl[buf][ar][ak + 8] = av1;
    *(uint4*)&Bsl[buf][br][bk] = bv0;
    *(uint4*)&Bsl[buf][br][bk + 8] = bv1;
    *(uint4*)&Bsl[buf][br][bk + 16] = bv2;
    *(uint4*)&Bsl[buf][br][bk + 24] = bv3;
    if (s < 15) {
      int k0 = (s + 1) * 64;
      const ushort_t* qa = outs + (size_t)(m0 + ar) * HH + k0 + ak;
      av0 = *(const uint4*)qa; av1 = *(const uint4*)(qa + 8);
      const ushort_t* qb = wlbf + (size_t)br * HH + k0 + bk;
      bv0 = *(const uint4*)qb; bv1 = *(const uint4*)(qb + 8);
      bv2 = *(const uint4*)(qb + 16); bv3 = *(const uint4*)(qb + 24);
    }
    __syncthreads();
#pragma unroll
    for (int kk = 0; kk < 64; kk += 32) {
      int koff = kk + (lane >> 4) * 8;
      bf16x8 a0 = *(const bf16x8*)&Asl[buf][wm * 32 + (lane & 15)][koff];
      bf16x8 a1 = *(const bf16x8*)&Asl[buf][wm * 32 + 16 + (lane & 15)][koff];
      bf16x8 b0 = *(const bf16x8*)&Bsl[buf][wn * 64 + (lane & 15)][koff];
      bf16x8 b1 = *(const bf16x8*)&Bsl[buf][wn * 64 + 16 + (lane & 15)][koff];
      bf16x8 b2 = *(const bf16x8*)&Bsl[buf][wn * 64 + 32 + (lane & 15)][koff];
      bf16x8 b3 = *(const bf16x8*)&Bsl[buf][wn * 64 + 48 + (lane & 15)][koff];
      acc[0][0] = MFMA(a0, b0, acc[0][0]);
      acc[0][1] = MFMA(a0, b1, acc[0][1]);
      acc[0][2] = MFMA(a0, b2, acc[0][2]);
      acc[0][3] = MFMA(a0, b3, acc[0][3]);
      acc[1][0] = MFMA(a1, b0, acc[1][0]);
      acc[1][1] = MFMA(a1, b1, acc[1][1]);
      acc[1][2] = MFMA(a1, b2, acc[1][2]);
      acc[1][3] = MFMA(a1, b3, acc[1][3]);
    }
    buf ^= 1;
  }
#pragma unroll
  for (int i = 0; i < 2; ++i)
#pragma unroll
    for (int j = 0; j < 4; ++j)
#pragma unroll
      for (int r = 0; r < 4; ++r) {
        int m = m0 + wm * 32 + i * 16 + (lane >> 4) * 4 + r;
        int v = wn * 64 + j * 16 + (lane & 15);
        out[(size_t)m * VV + v] = acc[i][j][r] + bl[v];
      }
}

// ----------------------------------------------------------------------------
extern "C" void kernel_launch(void* const* d_in, const int* in_sizes, int n_in,
                              void* d_out, int out_size, void* d_ws, size_t ws_size,
                              hipStream_t stream) {
  const float* x    = (const float*)d_in[0];
  const float* h_in = (const float*)d_in[1];
  const float* c_in = (const float*)d_in[2];
  const float* Wx   = (const float*)d_in[3];
  const float* Wh   = (const float*)d_in[4];
  const float* bx   = (const float*)d_in[5];
  const float* bh   = (const float*)d_in[6];
  const float* Wl   = (const float*)d_in[7];
  const float* bl   = (const float*)d_in[8];

  char* ws = (char*)d_ws;
  size_t off = 0;
  ushort_t* wcombT = (ushort_t*)(ws + off); off += (size_t)NG * KK * 2;        // 9.4 MB
  ushort_t* outs   = (ushort_t*)(ws + off); off += (size_t)BB * TT * HH * 2;   // 67 MB
  ushort_t* hbf    = (ushort_t*)(ws + off); off += (size_t)2 * BB * HH * 2;    // ping-pong
  float*    bias   = (float*)(ws + off);    off += (size_t)NG * 4;
  ushort_t* wlbf   = (ushort_t*)(ws + off); off += (size_t)VV * HH * 2;
  off = (off + 127) & ~(size_t)127;
  unsigned* bar    = (unsigned*)(ws + off); off += 544 * 4;

  float* out  = (float*)d_out;
  float* hout = out + (size_t)BB * TT * VV;
  float* cout = hout + (size_t)BB * HH;
  // xbf (8.4 MB) aliases the logits region of d_out (16.8 MB): read only by
  // lstm_persist, overwritten afterwards by logits_gemm. No ws growth.
  ushort_t* xbf = (ushort_t*)d_out;

  init_misc<<<dim3(512), dim3(256), 0, stream>>>(h_in, Wl, bx, bh,
                                                 hbf, wlbf, bias, bar);
  xconv<<<dim3(2048), dim3(256), 0, stream>>>(x, xbf);
  build_wcombT<<<dim3(36, 32, 4), dim3(256), 0, stream>>>(Wx, Wh, wcombT);

  {
    unsigned* outs32 = (unsigned*)outs;
    void* kargs[] = {(void*)&xbf, (void*)&wcombT, (void*)&bias, (void*)&hbf,
                     (void*)&outs32, (void*)&c_in, (void*)&hout, (void*)&cout,
                     (void*)&bar};
    hipError_t ce = hipLaunchCooperativeKernel((const void*)lstm_persist,
                                               dim3(256), dim3(256), kargs, 0,
                                               stream);
    if (ce != hipSuccess) {
      (void)hipGetLastError();  // clear sticky error; fall back to plain launch
      lstm_persist<<<dim3(256), dim3(256), 0, stream>>>(
          xbf, wcombT, bias, hbf, (unsigned*)outs, c_in, hout, cout, bar);
    }
  }

  logits_gemm<<<dim3(512), dim3(256), 0, stream>>>(outs, wlbf, bl, out);
}

// Round 6
// 1824.655 us; speedup vs baseline: 1.6692x; 1.6692x over previous
//
#include <hip/hip_runtime.h>
#include <hip/hip_bf16.h>

#define BB 128
#define TT 256
#define VV 128
#define HH 1024
#define NG 4096   // 4*H gate columns (permuted: n = hc*4 + kg)
#define KK 1152   // V + H fused reduction dim

typedef unsigned short ushort_t;
typedef short bf16x8 __attribute__((ext_vector_type(8)));
typedef float f32x4 __attribute__((ext_vector_type(4)));

__device__ __forceinline__ ushort_t f2bf(float f) {
  unsigned u = __builtin_bit_cast(unsigned, f);
  u += 0x7fffu + ((u >> 16) & 1u);   // RTNE
  return (ushort_t)(u >> 16);
}

__device__ __forceinline__ uint4 pack8(const float* p) {
  float4 a = *(const float4*)p;
  float4 b = *(const float4*)(p + 4);
  uint4 r;
  r.x = (unsigned)f2bf(a.x) | ((unsigned)f2bf(a.y) << 16);
  r.y = (unsigned)f2bf(a.z) | ((unsigned)f2bf(a.w) << 16);
  r.z = (unsigned)f2bf(b.x) | ((unsigned)f2bf(b.y) << 16);
  r.w = (unsigned)f2bf(b.z) | ((unsigned)f2bf(b.w) << 16);
  return r;
}

__device__ __forceinline__ f32x4 MFMA(bf16x8 a, bf16x8 b, f32x4 c) {
  return __builtin_amdgcn_mfma_f32_16x16x32_bf16(a, b, c, 0, 0, 0);
}

// fast sigmoid: native v_exp + rcp
__device__ __forceinline__ float fsig(float x) {
  return 1.f / (1.f + __expf(-x));
}

// L2-bypass coherent 16B load from LLC (sc0 sc1), immediate byte offset.
// Volatile asms keep program order among themselves; vmcnt retires in order.
#define LDH(idx, off)                                                   \
  asm volatile("global_load_dwordx4 %0, %1, off offset:" off " sc0 sc1" \
               : "=&v"(hf[idx]) : "v"(hrow))
#define VWAIT(n)                                          \
  asm volatile("s_waitcnt vmcnt(" #n ")" ::: "memory");   \
  __builtin_amdgcn_sched_barrier(0)

// ---------------- init: h0 bf16, Wl->bf16, bias = bx+bh (permuted), bar -----
__global__ void init_misc(const float* __restrict__ h_in, const float* __restrict__ Wl,
                          const float* __restrict__ bx, const float* __restrict__ bh,
                          ushort_t* __restrict__ hbf0, ushort_t* __restrict__ wlbf,
                          float* __restrict__ bias, unsigned* __restrict__ bar) {
  int i = blockIdx.x * blockDim.x + threadIdx.x;   // grid covers 131072 exactly
  hbf0[i] = f2bf(h_in[i]);
  wlbf[i] = f2bf(Wl[i]);
  if (i < NG) {
    int kg = i & 3, hc = i >> 2;
    bias[i] = bx[kg * HH + hc] + bh[kg * HH + hc];
  }
  if (i < 544) bar[i] = 0u;
}

// ---------------- x fp32 -> bf16 once (8 elems/thread) ----------------------
__global__ void xconv(const float* __restrict__ x, ushort_t* __restrict__ xbf) {
  size_t i = (size_t)(blockIdx.x * blockDim.x + threadIdx.x) * 8;
  *(uint4*)(xbf + i) = pack8(x + i);
}

// ------------- build WcombT[n][k] bf16, n = hc*4+kg, k = [x(128) | h(1024)] --
__global__ void build_wcombT(const float* __restrict__ Wx, const float* __restrict__ Wh,
                             ushort_t* __restrict__ wcombT) {
  __shared__ float tile[32][33];
  const int k0 = blockIdx.x * 32, hc0 = blockIdx.y * 32, kg = blockIdx.z;
  const int tid = threadIdx.x;
#pragma unroll
  for (int p = 0; p < 4; ++p) {
    int kk = (tid >> 5) + p * 8, hh = tid & 31;
    int k = k0 + kk, hc = hc0 + hh;
    float v = (k < VV) ? Wx[kg * VV * HH + k * HH + hc]
                       : Wh[kg * HH * HH + (k - VV) * HH + hc];
    tile[kk][hh] = v;
  }
  __syncthreads();
#pragma unroll
  for (int p = 0; p < 4; ++p) {
    int hh = (tid >> 5) + p * 8, kk = tid & 31;
    int n = (hc0 + hh) * 4 + kg;
    wcombT[n * KK + k0 + kk] = f2bf(tile[kk][hh]);
  }
}

// ---------------- persistent LSTM: all 256 timesteps, weights in VGPRs ------
// grid 256 (mb = blk&3 -> 32 batch rows, nb = blk>>2 -> 64 gate cols), 4 waves
// h exchange: WT stores -> LLC; readers use sc0 sc1 bypass loads. NO fences,
// NO buffer_inv anywhere in the loop (L2 keeps weights/x hot for 256 steps).
__global__ __launch_bounds__(256, 1) void lstm_persist(
    const ushort_t* __restrict__ xbf, const ushort_t* __restrict__ wcombT,
    const float* __restrict__ bias, ushort_t* __restrict__ hping,
    unsigned* __restrict__ outs32, const float* __restrict__ c_in,
    float* __restrict__ hout, float* __restrict__ cout,
    unsigned* __restrict__ bar) {
  const int tid = threadIdx.x;
  const int b0 = (blockIdx.x & 3) * 32;
  const int n0 = (blockIdx.x >> 2) * 64;
  const int grp = blockIdx.x & 7;                  // round-robin -> per-XCD group
  const int wave = tid >> 6, lane = tid & 63;
  const int wm = wave >> 1, wn = wave & 1;
  const int c15 = lane & 15, q = lane >> 4;
  const int kg = lane & 3;
  const bool isg = (kg == 2);
  const int arow = wm * 16 + c15;                  // A-fragment row (0..31)
  const int rbase = b0 + wm * 16 + q * 4;
  const int hu0 = (n0 >> 2) + wn * 8 + (c15 >> 2); // + j*4

  // ---- one-time: B fragments into registers ----
  bf16x8 breg[36][2];
#pragma unroll
  for (int ks = 0; ks < 36; ++ks)
#pragma unroll
    for (int j = 0; j < 2; ++j)
      breg[ks][j] = *(const bf16x8*)(wcombT +
          (size_t)(n0 + wn * 32 + j * 16 + c15) * KK + ks * 32 + q * 8);

  float biasr[2];
#pragma unroll
  for (int j = 0; j < 2; ++j)
    biasr[j] = bias[n0 + wn * 32 + j * 16 + c15];

  float cr[2][4];
#pragma unroll
  for (int j = 0; j < 2; ++j)
#pragma unroll
    for (int r = 0; r < 4; ++r)
      cr[j][r] = c_in[(size_t)(rbase + r) * HH + hu0 + j * 4];

  const ushort_t* xlane = xbf + (size_t)(b0 + arow) * (TT * VV) + q * 8;

  // x fragments for t = 0, and x-part MFMAs for t = 0
  bf16x8 xr[4];
#pragma unroll
  for (int ks = 0; ks < 4; ++ks)
    xr[ks] = *(const bf16x8*)(xlane + ks * 32);

  f32x4 a0e = {0.f,0.f,0.f,0.f}, a0o = {0.f,0.f,0.f,0.f};
  f32x4 a1e = {0.f,0.f,0.f,0.f}, a1o = {0.f,0.f,0.f,0.f};
  a0e = MFMA(xr[0], breg[0][0], a0e);
  a1e = MFMA(xr[0], breg[0][1], a1e);
  a0o = MFMA(xr[1], breg[1][0], a0o);
  a1o = MFMA(xr[1], breg[1][1], a1o);
  a0e = MFMA(xr[2], breg[2][0], a0e);
  a1e = MFMA(xr[2], breg[2][1], a1e);
  a0o = MFMA(xr[3], breg[3][0], a0o);
  a1o = MFMA(xr[3], breg[3][1], a1o);

  for (int t = 0; t < TT; ++t) {
    const ushort_t* hc_ = hping + (size_t)(t & 1) * BB * HH;
    ushort_t* hn_ = hping + (size_t)((t + 1) & 1) * BB * HH;
    const ushort_t* hrow = hc_ + (size_t)(b0 + arow) * HH + q * 8;

    // ---- h-part GEMM: L2-bypass coherent loads, pipelined counted waits ----
    // Counted-wait safety: vmcnt(N) here always has N <= (# of our volatile
    // vmem ops issued after the awaited group), and vmcnt retires in order,
    // so compiler-inserted vmem ops can only make the wait stricter.
    bf16x8 hf[32];
    __builtin_amdgcn_sched_barrier(0);
    LDH(0, "0");    LDH(1, "64");   LDH(2, "128");  LDH(3, "192");
    LDH(4, "256");  LDH(5, "320");  LDH(6, "384");  LDH(7, "448");
    LDH(8, "512");  LDH(9, "576");  LDH(10, "640"); LDH(11, "704");
    LDH(12, "768"); LDH(13, "832"); LDH(14, "896"); LDH(15, "960");
    VWAIT(8);                                   // h[0..7] ready
#pragma unroll
    for (int hs = 0; hs < 8; hs += 2) {
      a0e = MFMA(hf[hs], breg[4 + hs][0], a0e);
      a1e = MFMA(hf[hs], breg[4 + hs][1], a1e);
      a0o = MFMA(hf[hs + 1], breg[5 + hs][0], a0o);
      a1o = MFMA(hf[hs + 1], breg[5 + hs][1], a1o);
    }
    __builtin_amdgcn_sched_barrier(0);
    LDH(16, "1024"); LDH(17, "1088"); LDH(18, "1152"); LDH(19, "1216");
    LDH(20, "1280"); LDH(21, "1344"); LDH(22, "1408"); LDH(23, "1472");
    VWAIT(8);                                   // h[8..15] ready
#pragma unroll
    for (int hs = 8; hs < 16; hs += 2) {
      a0e = MFMA(hf[hs], breg[4 + hs][0], a0e);
      a1e = MFMA(hf[hs], breg[4 + hs][1], a1e);
      a0o = MFMA(hf[hs + 1], breg[5 + hs][0], a0o);
      a1o = MFMA(hf[hs + 1], breg[5 + hs][1], a1o);
    }
    __builtin_amdgcn_sched_barrier(0);
    LDH(24, "1536"); LDH(25, "1600"); LDH(26, "1664"); LDH(27, "1728");
    LDH(28, "1792"); LDH(29, "1856"); LDH(30, "1920"); LDH(31, "1984");
    VWAIT(8);                                   // h[16..23] ready
#pragma unroll
    for (int hs = 16; hs < 24; hs += 2) {
      a0e = MFMA(hf[hs], breg[4 + hs][0], a0e);
      a1e = MFMA(hf[hs], breg[4 + hs][1], a1e);
      a0o = MFMA(hf[hs + 1], breg[5 + hs][0], a0o);
      a1o = MFMA(hf[hs + 1], breg[5 + hs][1], a1o);
    }
    __builtin_amdgcn_sched_barrier(0);
    VWAIT(0);                                   // h[24..31] ready
#pragma unroll
    for (int hs = 24; hs < 32; hs += 2) {
      a0e = MFMA(hf[hs], breg[4 + hs][0], a0e);
      a1e = MFMA(hf[hs], breg[4 + hs][1], a1e);
      a0o = MFMA(hf[hs + 1], breg[5 + hs][0], a0o);
      a1o = MFMA(hf[hs + 1], breg[5 + hs][1], a1o);
    }
    __builtin_amdgcn_sched_barrier(0);
    f32x4 g0 = a0e + a0o, g1 = a1e + a1o;

    // ---- prefetch x fragments for t+1 (compiler-managed loads) ----
    if (t < TT - 1) {
#pragma unroll
      for (int ks = 0; ks < 4; ++ks)
        xr[ks] = *(const bf16x8*)(xlane + (t + 1) * VV + ks * 32);
    }

    // ---- pointwise LSTM in registers (4 gates live in 4-lane groups) ----
    const bool last = (t == TT - 1);
#pragma unroll
    for (int j = 0; j < 2; ++j) {
      f32x4 gj = j ? g1 : g0;
#pragma unroll
      for (int r = 0; r < 4; ++r) {
        float pre = gj[r] + biasr[j];
        float sx = isg ? pre + pre : pre;
        float sg = fsig(sx);
        float a = isg ? sg + sg - 1.f : sg;     // own gate activation
        float fv = __shfl_xor(a, 1);
        float gv = __shfl_xor(a, 2);
        float ov = __shfl_xor(fv, 2);
        float cn = fv * cr[j][r] + a * gv;      // valid on kg==0 lanes
        cr[j][r] = cn;
        float hn = ov * (2.f * fsig(cn + cn) - 1.f);   // ov * tanh(cn)
        unsigned hb = f2bf(hn), ob = f2bf(ov);
        unsigned hbp = (unsigned)__shfl_xor((int)hb, 4);
        unsigned obp = (unsigned)__shfl_xor((int)ob, 4);
        if ((lane & 7) == 0) {                  // kg==0 && even hu pair
          int b = rbase + r, hu = hu0 + j * 4;
          // h: write-through to LLC (sc0 sc1); readers bypass-load from LLC
          __hip_atomic_store((unsigned*)(hn_ + (size_t)b * HH + hu),
                             hb | (hbp << 16), __ATOMIC_RELAXED,
                             __HIP_MEMORY_SCOPE_AGENT);
          outs32[(((size_t)b * TT + t) * HH + hu) >> 1] = ob | (obp << 16);
        }
        if (last && kg == 0) {
          int b = rbase + r, hu = hu0 + j * 4;
          hout[(size_t)b * HH + hu] = hn;
          cout[(size_t)b * HH + hu] = cn;
        }
      }
    }

    if (t < TT - 1) {
      // ---- barrier: arrive -> overlap x-MFMAs(t+1) -> single-hop poll ----
      __syncthreads();   // vmcnt(0): all waves' WT h-stores visible at LLC
      if (tid == 0)
        __hip_atomic_fetch_add(bar + 32 * (1 + grp), 1u, __ATOMIC_RELAXED,
                               __HIP_MEMORY_SCOPE_AGENT);
      // x-part MFMAs for t+1 (register-only; overlaps barrier wait)
      a0e = (f32x4){0.f,0.f,0.f,0.f}; a0o = (f32x4){0.f,0.f,0.f,0.f};
      a1e = (f32x4){0.f,0.f,0.f,0.f}; a1o = (f32x4){0.f,0.f,0.f,0.f};
      a0e = MFMA(xr[0], breg[0][0], a0e);
      a1e = MFMA(xr[0], breg[0][1], a1e);
      a0o = MFMA(xr[1], breg[1][0], a0o);
      a1o = MFMA(xr[1], breg[1][1], a1o);
      a0e = MFMA(xr[2], breg[2][0], a0e);
      a1e = MFMA(xr[2], breg[2][1], a1e);
      a0o = MFMA(xr[3], breg[3][0], a0o);
      a1o = MFMA(xr[3], breg[3][1], a1o);
      // wave 0: each lane polls one of 8 sub-counters (bypass atomic loads)
      if (tid < 64) {
        const unsigned* ctr = bar + 32 * (1 + (tid & 7));
        unsigned tgt = 32u * (unsigned)(t + 1);
        while (true) {
          unsigned v = __hip_atomic_load(ctr, __ATOMIC_RELAXED,
                                         __HIP_MEMORY_SCOPE_AGENT);
          if (__all(v >= tgt)) break;
          __builtin_amdgcn_s_sleep(1);
        }
        // NO acquire fence: h reads bypass L1/L2, so no invalidate needed
      }
      __syncthreads();
      __builtin_amdgcn_sched_barrier(0);
    }
  }
}

// ---------------- logits = outs(bf16) @ Wl^T + bl ---------------------------
// grid 512, 256 threads (waves 2x2), WG tile 64(M) x 128(N=V)
__global__ __launch_bounds__(256) void logits_gemm(
    const ushort_t* __restrict__ outs, const ushort_t* __restrict__ wlbf,
    const float* __restrict__ bl, float* __restrict__ out) {
  __shared__ __align__(16) ushort_t Asl[2][64][72];
  __shared__ __align__(16) ushort_t Bsl[2][128][72];
  const int tid = threadIdx.x;
  const int m0 = blockIdx.x * 64;
  const int wave = tid >> 6, lane = tid & 63;
  const int wm = wave >> 1, wn = wave & 1;
  const int ar = tid >> 2, ak = (tid & 3) * 16;
  const int br = tid >> 1, bk = (tid & 1) * 32;

  f32x4 acc[2][4];
#pragma unroll
  for (int i = 0; i < 2; ++i)
#pragma unroll
    for (int j = 0; j < 4; ++j) acc[i][j] = {0.f, 0.f, 0.f, 0.f};

  const ushort_t* pa = outs + (size_t)(m0 + ar) * HH + ak;
  uint4 av0 = *(const uint4*)pa, av1 = *(const uint4*)(pa + 8);
  const ushort_t* pb = wlbf + (size_t)br * HH + bk;
  uint4 bv0 = *(const uint4*)pb, bv1 = *(const uint4*)(pb + 8);
  uint4 bv2 = *(const uint4*)(pb + 16), bv3 = *(const uint4*)(pb + 24);

  int buf = 0;
  for (int s = 0; s < 16; ++s) {
    *(uint4*)&Asl[buf][ar][ak] = av0;
    *(uint4*)&Asl[buf][ar][ak + 8] = av1;
    *(uint4*)&Bsl[buf][br][bk] = bv0;
    *(uint4*)&Bsl[buf][br][bk + 8] = bv1;
    *(uint4*)&Bsl[buf][br][bk + 16] = bv2;
    *(uint4*)&Bsl[buf][br][bk + 24] = bv3;
    if (s < 15) {
      int k0 = (s + 1) * 64;
      const ushort_t* qa = outs + (size_t)(m0 + ar) * HH + k0 + ak;
      av0 = *(const uint4*)qa; av1 = *(const uint4*)(qa + 8);
      const ushort_t* qb = wlbf + (size_t)br * HH + k0 + bk;
      bv0 = *(const uint4*)qb; bv1 = *(const uint4*)(qb + 8);
      bv2 = *(const uint4*)(qb + 16); bv3 = *(const uint4*)(qb + 24);
    }
    __syncthreads();
#pragma unroll
    for (int kk = 0; kk < 64; kk += 32) {
      int koff = kk + (lane >> 4) * 8;
      bf16x8 a0 = *(const bf16x8*)&Asl[buf][wm * 32 + (lane & 15)][koff];
      bf16x8 a1 = *(const bf16x8*)&Asl[buf][wm * 32 + 16 + (lane & 15)][koff];
      bf16x8 b0 = *(const bf16x8*)&Bsl[buf][wn * 64 + (lane & 15)][koff];
      bf16x8 b1 = *(const bf16x8*)&Bsl[buf][wn * 64 + 16 + (lane & 15)][koff];
      bf16x8 b2 = *(const bf16x8*)&Bsl[buf][wn * 64 + 32 + (lane & 15)][koff];
      bf16x8 b3 = *(const bf16x8*)&Bsl[buf][wn * 64 + 48 + (lane & 15)][koff];
      acc[0][0] = MFMA(a0, b0, acc[0][0]);
      acc[0][1] = MFMA(a0, b1, acc[0][1]);
      acc[0][2] = MFMA(a0, b2, acc[0][2]);
      acc[0][3] = MFMA(a0, b3, acc[0][3]);
      acc[1][0] = MFMA(a1, b0, acc[1][0]);
      acc[1][1] = MFMA(a1, b1, acc[1][1]);
      acc[1][2] = MFMA(a1, b2, acc[1][2]);
      acc[1][3] = MFMA(a1, b3, acc[1][3]);
    }
    buf ^= 1;
  }
#pragma unroll
  for (int i = 0; i < 2; ++i)
#pragma unroll
    for (int j = 0; j < 4; ++j)
#pragma unroll
      for (int r = 0; r < 4; ++r) {
        int m = m0 + wm * 32 + i * 16 + (lane >> 4) * 4 + r;
        int v = wn * 64 + j * 16 + (lane & 15);
        out[(size_t)m * VV + v] = acc[i][j][r] + bl[v];
      }
}

// ----------------------------------------------------------------------------
extern "C" void kernel_launch(void* const* d_in, const int* in_sizes, int n_in,
                              void* d_out, int out_size, void* d_ws, size_t ws_size,
                              hipStream_t stream) {
  const float* x    = (const float*)d_in[0];
  const float* h_in = (const float*)d_in[1];
  const float* c_in = (const float*)d_in[2];
  const float* Wx   = (const float*)d_in[3];
  const float* Wh   = (const float*)d_in[4];
  const float* bx   = (const float*)d_in[5];
  const float* bh   = (const float*)d_in[6];
  const float* Wl   = (const float*)d_in[7];
  const float* bl   = (const float*)d_in[8];

  char* ws = (char*)d_ws;
  size_t off = 0;
  ushort_t* wcombT = (ushort_t*)(ws + off); off += (size_t)NG * KK * 2;        // 9.4 MB
  ushort_t* outs   = (ushort_t*)(ws + off); off += (size_t)BB * TT * HH * 2;   // 67 MB
  ushort_t* hbf    = (ushort_t*)(ws + off); off += (size_t)2 * BB * HH * 2;    // ping-pong
  float*    bias   = (float*)(ws + off);    off += (size_t)NG * 4;
  ushort_t* wlbf   = (ushort_t*)(ws + off); off += (size_t)VV * HH * 2;
  off = (off + 127) & ~(size_t)127;
  unsigned* bar    = (unsigned*)(ws + off); off += 544 * 4;

  float* out  = (float*)d_out;
  float* hout = out + (size_t)BB * TT * VV;
  float* cout = hout + (size_t)BB * HH;
  // xbf (8.4 MB) aliases the logits region of d_out (16.8 MB): read only by
  // lstm_persist, overwritten afterwards by logits_gemm. No ws growth.
  ushort_t* xbf = (ushort_t*)d_out;

  init_misc<<<dim3(512), dim3(256), 0, stream>>>(h_in, Wl, bx, bh,
                                                 hbf, wlbf, bias, bar);
  xconv<<<dim3(2048), dim3(256), 0, stream>>>(x, xbf);
  build_wcombT<<<dim3(36, 32, 4), dim3(256), 0, stream>>>(Wx, Wh, wcombT);

  {
    unsigned* outs32 = (unsigned*)outs;
    void* kargs[] = {(void*)&xbf, (void*)&wcombT, (void*)&bias, (void*)&hbf,
                     (void*)&outs32, (void*)&c_in, (void*)&hout, (void*)&cout,
                     (void*)&bar};
    hipError_t ce = hipLaunchCooperativeKernel((const void*)lstm_persist,
                                               dim3(256), dim3(256), kargs, 0,
                                               stream);
    if (ce != hipSuccess) {
      (void)hipGetLastError();  // clear sticky error; fall back to plain launch
      lstm_persist<<<dim3(256), dim3(256), 0, stream>>>(
          xbf, wcombT, bias, hbf, (unsigned*)outs, c_in, hout, cout, bar);
    }
  }

  logits_gemm<<<dim3(512), dim3(256), 0, stream>>>(outs, wlbf, bl, out);
}

// Round 7
// 1733.452 us; speedup vs baseline: 1.7571x; 1.0526x over previous
//
#include <hip/hip_runtime.h>
#include <hip/hip_bf16.h>

#define BB 128
#define TT 256
#define VV 128
#define HH 1024
#define NG 4096   // 4*H gate columns (permuted: n = hc*4 + kg)
#define KK 1152   // V + H fused reduction dim
#define TVV (TT * VV)

typedef unsigned short ushort_t;
typedef short bf16x8 __attribute__((ext_vector_type(8)));
typedef float f32x4 __attribute__((ext_vector_type(4)));

__device__ __forceinline__ ushort_t f2bf(float f) {
  unsigned u = __builtin_bit_cast(unsigned, f);
  u += 0x7fffu + ((u >> 16) & 1u);   // RTNE
  return (ushort_t)(u >> 16);
}

__device__ __forceinline__ uint4 pack8(const float* p) {
  float4 a = *(const float4*)p;
  float4 b = *(const float4*)(p + 4);
  uint4 r;
  r.x = (unsigned)f2bf(a.x) | ((unsigned)f2bf(a.y) << 16);
  r.y = (unsigned)f2bf(a.z) | ((unsigned)f2bf(a.w) << 16);
  r.z = (unsigned)f2bf(b.x) | ((unsigned)f2bf(b.y) << 16);
  r.w = (unsigned)f2bf(b.z) | ((unsigned)f2bf(b.w) << 16);
  return r;
}

__device__ __forceinline__ f32x4 MFMA(bf16x8 a, bf16x8 b, f32x4 c) {
  return __builtin_amdgcn_mfma_f32_16x16x32_bf16(a, b, c, 0, 0, 0);
}

__device__ __forceinline__ float fsig(float x) {
  return 1.f / (1.f + __expf(-x));
}

// L2-bypass coherent 16B load from LLC (sc0 sc1), immediate byte offset.
#define LDH(dst, base, off)                                             \
  asm volatile("global_load_dwordx4 %0, %1, off offset:" off " sc0 sc1" \
               : "=&v"(dst) : "v"(base))
#define VWAIT(n)                                          \
  asm volatile("s_waitcnt vmcnt(" #n ")" ::: "memory");   \
  __builtin_amdgcn_sched_barrier(0)

// ---------------- init: h0 bf16, Wl->bf16, bias = bx+bh (permuted), bar -----
__global__ void init_misc(const float* __restrict__ h_in, const float* __restrict__ Wl,
                          const float* __restrict__ bx, const float* __restrict__ bh,
                          ushort_t* __restrict__ hbf0, ushort_t* __restrict__ wlbf,
                          float* __restrict__ bias, unsigned* __restrict__ bar) {
  int i = blockIdx.x * blockDim.x + threadIdx.x;   // grid covers 131072 exactly
  hbf0[i] = f2bf(h_in[i]);
  wlbf[i] = f2bf(Wl[i]);
  if (i < NG) {
    int kg = i & 3, hc = i >> 2;
    bias[i] = bx[kg * HH + hc] + bh[kg * HH + hc];
  }
  if (i < 1056) bar[i] = 0u;
}

// ---------------- x fp32 -> bf16 once (8 elems/thread) ----------------------
__global__ void xconv(const float* __restrict__ x, ushort_t* __restrict__ xbf) {
  size_t i = (size_t)(blockIdx.x * blockDim.x + threadIdx.x) * 8;
  *(uint4*)(xbf + i) = pack8(x + i);
}

// ------------- build WcombT[n][k] bf16, n = hc*4+kg, k = [x(128) | h(1024)] --
__global__ void build_wcombT(const float* __restrict__ Wx, const float* __restrict__ Wh,
                             ushort_t* __restrict__ wcombT) {
  __shared__ float tile[32][33];
  const int k0 = blockIdx.x * 32, hc0 = blockIdx.y * 32, kg = blockIdx.z;
  const int tid = threadIdx.x;
#pragma unroll
  for (int p = 0; p < 4; ++p) {
    int kk = (tid >> 5) + p * 8, hh = tid & 31;
    int k = k0 + kk, hc = hc0 + hh;
    float v = (k < VV) ? Wx[kg * VV * HH + k * HH + hc]
                       : Wh[kg * HH * HH + (k - VV) * HH + hc];
    tile[kk][hh] = v;
  }
  __syncthreads();
#pragma unroll
  for (int p = 0; p < 4; ++p) {
    int hh = (tid >> 5) + p * 8, kk = tid & 31;
    int n = (hc0 + hh) * 4 + kg;
    wcombT[n * KK + k0 + kk] = f2bf(tile[kk][hh]);
  }
}

// ---------------- persistent LSTM: K-split waves, weights fully resident ----
// grid 256: mb = blk&3 (32 batch rows), nb = blk>>2 (64 gate cols).
// Waves: ws = wave>>1 (K-half), wn = wave&1 (32-col half). Each wave: M=32.
// Per-step cross-wave K-reduction via 8KB LDS. Per-mb barrier (64 blocks).
__global__ __launch_bounds__(256, 1) void lstm_persist(
    const ushort_t* __restrict__ xbf, const ushort_t* __restrict__ wcombT,
    const float* __restrict__ bias, ushort_t* __restrict__ hping,
    unsigned* __restrict__ outs32, const float* __restrict__ c_in,
    float* __restrict__ hout, float* __restrict__ cout,
    unsigned* __restrict__ bar) {
  __shared__ __align__(16) float red[2048];        // 4 zones x 512 f32 = 8 KB

  const int tid = threadIdx.x;
  const int mb = blockIdx.x & 3;
  const int b0 = mb * 32;
  const int n0 = (blockIdx.x >> 2) * 64;
  const int sub = (blockIdx.x >> 2) & 7;           // 8 counters per mb group
  const int wave = tid >> 6, lane = tid & 63;
  const int ws = wave >> 1, wn = wave & 1;
  const int c15 = lane & 15, q = lane >> 4;
  const int kg = lane & 3;
  const bool isg = (kg == 2);
  const int rbase = b0 + ws * 16 + q * 4;
  const int hu0 = (n0 >> 2) + wn * 8 + (c15 >> 2); // + j*4

  // ---- one-time: weights into registers (fits now: 128+16 VGPR/wave) ----
  bf16x8 bregh[16][2];                             // h k-slices ws*16 .. +15
#pragma unroll
  for (int i = 0; i < 16; ++i)
#pragma unroll
    for (int j = 0; j < 2; ++j)
      bregh[i][j] = *(const bf16x8*)(wcombT +
          (size_t)(n0 + wn * 32 + j * 16 + c15) * KK +
          VV + (ws * 16 + i) * 32 + q * 8);

  bf16x8 bregx[4][2];                              // x k-slices 0..3 (ws0 use)
#pragma unroll
  for (int i = 0; i < 4; ++i)
#pragma unroll
    for (int j = 0; j < 2; ++j)
      bregx[i][j] = *(const bf16x8*)(wcombT +
          (size_t)(n0 + wn * 32 + j * 16 + c15) * KK + i * 32 + q * 8);

  float biasr[2];
#pragma unroll
  for (int j = 0; j < 2; ++j)
    biasr[j] = bias[n0 + wn * 32 + j * 16 + c15];

  float cr[2][4];
#pragma unroll
  for (int j = 0; j < 2; ++j)
#pragma unroll
    for (int r = 0; r < 4; ++r)
      cr[j][r] = c_in[(size_t)(rbase + r) * HH + hu0 + j * 4];

  const ushort_t* xlane0 = xbf + (size_t)(b0 + c15) * TVV + q * 8;
  const ushort_t* xlane1 = xbf + (size_t)(b0 + 16 + c15) * TVV + q * 8;

  bf16x8 xr0[4], xr1[4];
  if (ws == 0) {
#pragma unroll
    for (int i = 0; i < 4; ++i) {
      xr0[i] = *(const bf16x8*)(xlane0 + i * 32);
      xr1[i] = *(const bf16x8*)(xlane1 + i * 32);
    }
  }

  // drain ALL prologue vmem before entering counted-vmcnt territory
  asm volatile("s_waitcnt vmcnt(0)" ::: "memory");
  __builtin_amdgcn_sched_barrier(0);

  // acc init for t=0 (+ x MFMAs on ws0)
  f32x4 acc0[2], acc1[2];
#pragma unroll
  for (int j = 0; j < 2; ++j) {
    acc0[j] = (f32x4){0.f, 0.f, 0.f, 0.f};
    acc1[j] = (f32x4){0.f, 0.f, 0.f, 0.f};
  }
  if (ws == 0) {
#pragma unroll
    for (int i = 0; i < 4; ++i)
#pragma unroll
      for (int j = 0; j < 2; ++j) {
        acc0[j] = MFMA(xr0[i], bregx[i][j], acc0[j]);
        acc1[j] = MFMA(xr1[i], bregx[i][j], acc1[j]);
      }
  }

  for (int t = 0; t < TT; ++t) {
    const ushort_t* hc_ = hping + (size_t)(t & 1) * BB * HH;
    ushort_t* hn_ = hping + (size_t)((t + 1) & 1) * BB * HH;
    // h k-cols for this wave start at element ws*512 of the row
    const ushort_t* hrow0 = hc_ + (size_t)(b0 + c15) * HH + ws * 512 + q * 8;
    const ushort_t* hrow1 = hc_ + (size_t)(b0 + 16 + c15) * HH + ws * 512 + q * 8;

    // ---- h GEMM: 16 slices x 2 rows, bypass loads, counted waits ----
    bf16x8 hf[32];
    __builtin_amdgcn_sched_barrier(0);
    LDH(hf[0], hrow0, "0");    LDH(hf[1], hrow1, "0");
    LDH(hf[2], hrow0, "64");   LDH(hf[3], hrow1, "64");
    LDH(hf[4], hrow0, "128");  LDH(hf[5], hrow1, "128");
    LDH(hf[6], hrow0, "192");  LDH(hf[7], hrow1, "192");
    LDH(hf[8], hrow0, "256");  LDH(hf[9], hrow1, "256");
    LDH(hf[10], hrow0, "320"); LDH(hf[11], hrow1, "320");
    LDH(hf[12], hrow0, "384"); LDH(hf[13], hrow1, "384");
    LDH(hf[14], hrow0, "448"); LDH(hf[15], hrow1, "448");
    VWAIT(8);                                   // slices 0..3 ready
#pragma unroll
    for (int s = 0; s < 4; ++s) {
      acc0[0] = MFMA(hf[2 * s], bregh[s][0], acc0[0]);
      acc0[1] = MFMA(hf[2 * s], bregh[s][1], acc0[1]);
      acc1[0] = MFMA(hf[2 * s + 1], bregh[s][0], acc1[0]);
      acc1[1] = MFMA(hf[2 * s + 1], bregh[s][1], acc1[1]);
    }
    __builtin_amdgcn_sched_barrier(0);
    LDH(hf[16], hrow0, "512"); LDH(hf[17], hrow1, "512");
    LDH(hf[18], hrow0, "576"); LDH(hf[19], hrow1, "576");
    LDH(hf[20], hrow0, "640"); LDH(hf[21], hrow1, "640");
    LDH(hf[22], hrow0, "704"); LDH(hf[23], hrow1, "704");
    VWAIT(8);                                   // slices 4..7 ready
#pragma unroll
    for (int s = 4; s < 8; ++s) {
      acc0[0] = MFMA(hf[2 * s], bregh[s][0], acc0[0]);
      acc0[1] = MFMA(hf[2 * s], bregh[s][1], acc0[1]);
      acc1[0] = MFMA(hf[2 * s + 1], bregh[s][0], acc1[0]);
      acc1[1] = MFMA(hf[2 * s + 1], bregh[s][1], acc1[1]);
    }
    __builtin_amdgcn_sched_barrier(0);
    LDH(hf[24], hrow0, "768"); LDH(hf[25], hrow1, "768");
    LDH(hf[26], hrow0, "832"); LDH(hf[27], hrow1, "832");
    LDH(hf[28], hrow0, "896"); LDH(hf[29], hrow1, "896");
    LDH(hf[30], hrow0, "960"); LDH(hf[31], hrow1, "960");
    VWAIT(8);                                   // slices 8..11 ready
#pragma unroll
    for (int s = 8; s < 12; ++s) {
      acc0[0] = MFMA(hf[2 * s], bregh[s][0], acc0[0]);
      acc0[1] = MFMA(hf[2 * s], bregh[s][1], acc0[1]);
      acc1[0] = MFMA(hf[2 * s + 1], bregh[s][0], acc1[0]);
      acc1[1] = MFMA(hf[2 * s + 1], bregh[s][1], acc1[1]);
    }
    __builtin_amdgcn_sched_barrier(0);
    VWAIT(0);                                   // slices 12..15 ready
#pragma unroll
    for (int s = 12; s < 16; ++s) {
      acc0[0] = MFMA(hf[2 * s], bregh[s][0], acc0[0]);
      acc0[1] = MFMA(hf[2 * s], bregh[s][1], acc0[1]);
      acc1[0] = MFMA(hf[2 * s + 1], bregh[s][0], acc1[0]);
      acc1[1] = MFMA(hf[2 * s + 1], bregh[s][1], acc1[1]);
    }
    __builtin_amdgcn_sched_barrier(0);

    // ---- prefetch x fragments for t+1 (compiler loads; after counted zone) --
    if (ws == 0 && t < TT - 1) {
#pragma unroll
      for (int i = 0; i < 4; ++i) {
        xr0[i] = *(const bf16x8*)(xlane0 + (t + 1) * VV + i * 32);
        xr1[i] = *(const bf16x8*)(xlane1 + (t + 1) * VV + i * 32);
      }
    }

    // ---- cross-wave K-reduction: ship the non-owned M-tile via LDS ----
    {
      int zw = (wn * 2 + 1 - ws) * 512 + c15 * 16 + q * 4;
      if (ws == 0) {
        *(f32x4*)(red + zw) = acc1[0];
        *(f32x4*)(red + zw + 256) = acc1[1];
      } else {
        *(f32x4*)(red + zw) = acc0[0];
        *(f32x4*)(red + zw + 256) = acc0[1];
      }
    }
    __syncthreads();
    int zr = (wn * 2 + ws) * 512 + c15 * 16 + q * 4;
    f32x4 g0 = (ws ? acc1[0] : acc0[0]) + *(const f32x4*)(red + zr);
    f32x4 g1 = (ws ? acc1[1] : acc0[1]) + *(const f32x4*)(red + zr + 256);

    // ---- pointwise LSTM in registers (4 gates live in 4-lane groups) ----
    const bool last = (t == TT - 1);
#pragma unroll
    for (int j = 0; j < 2; ++j) {
      f32x4 gj = j ? g1 : g0;
#pragma unroll
      for (int r = 0; r < 4; ++r) {
        float pre = gj[r] + biasr[j];
        float sx = isg ? pre + pre : pre;
        float sg = fsig(sx);
        float a = isg ? sg + sg - 1.f : sg;     // own gate activation
        float fv = __shfl_xor(a, 1);
        float gv = __shfl_xor(a, 2);
        float ov = __shfl_xor(fv, 2);
        float cn = fv * cr[j][r] + a * gv;      // valid on kg==0 lanes
        cr[j][r] = cn;
        float hn = ov * (2.f * fsig(cn + cn) - 1.f);   // ov * tanh(cn)
        unsigned hb = f2bf(hn), ob = f2bf(ov);
        unsigned hbp = (unsigned)__shfl_xor((int)hb, 4);
        unsigned obp = (unsigned)__shfl_xor((int)ob, 4);
        if ((lane & 7) == 0) {                  // kg==0 && even hu pair
          int b = rbase + r, hu = hu0 + j * 4;
          __hip_atomic_store((unsigned*)(hn_ + (size_t)b * HH + hu),
                             hb | (hbp << 16), __ATOMIC_RELAXED,
                             __HIP_MEMORY_SCOPE_AGENT);
          outs32[(((size_t)b * TT + t) * HH + hu) >> 1] = ob | (obp << 16);
        }
        if (last && kg == 0) {
          int b = rbase + r, hu = hu0 + j * 4;
          hout[(size_t)b * HH + hu] = hn;
          cout[(size_t)b * HH + hu] = cn;
        }
      }
    }

    if (t < TT - 1) {
      // ---- per-mb barrier: arrive -> overlap x-MFMAs(t+1) -> poll ----
      __syncthreads();   // vmcnt(0): all waves' WT h-stores visible at LLC
      if (tid == 0)
        __hip_atomic_fetch_add(bar + 32 * (1 + mb * 8 + sub), 1u,
                               __ATOMIC_RELAXED, __HIP_MEMORY_SCOPE_AGENT);
      // acc re-init for t+1 (+ x MFMAs on ws0; overlaps barrier wait)
#pragma unroll
      for (int j = 0; j < 2; ++j) {
        acc0[j] = (f32x4){0.f, 0.f, 0.f, 0.f};
        acc1[j] = (f32x4){0.f, 0.f, 0.f, 0.f};
      }
      if (ws == 0) {
#pragma unroll
        for (int i = 0; i < 4; ++i)
#pragma unroll
          for (int j = 0; j < 2; ++j) {
            acc0[j] = MFMA(xr0[i], bregx[i][j], acc0[j]);
            acc1[j] = MFMA(xr1[i], bregx[i][j], acc1[j]);
          }
      }
      // wave 0: lanes poll the 8 counters of this mb group
      if (tid < 64) {
        const unsigned* ctr = bar + 32 * (1 + mb * 8 + (tid & 7));
        unsigned tgt = 8u * (unsigned)(t + 1);
        while (true) {
          unsigned v = __hip_atomic_load(ctr, __ATOMIC_RELAXED,
                                         __HIP_MEMORY_SCOPE_AGENT);
          if (__all(v >= tgt)) break;
          __builtin_amdgcn_s_sleep(1);
        }
        // NO acquire fence: h reads bypass L1/L2 (sc0 sc1)
      }
      __syncthreads();
      __builtin_amdgcn_sched_barrier(0);
    }
  }
}

// ---------------- logits = outs(bf16) @ Wl^T + bl ---------------------------
// grid 512, 256 threads (waves 2x2), WG tile 64(M) x 128(N=V)
__global__ __launch_bounds__(256) void logits_gemm(
    const ushort_t* __restrict__ outs, const ushort_t* __restrict__ wlbf,
    const float* __restrict__ bl, float* __restrict__ out) {
  __shared__ __align__(16) ushort_t Asl[2][64][72];
  __shared__ __align__(16) ushort_t Bsl[2][128][72];
  const int tid = threadIdx.x;
  const int m0 = blockIdx.x * 64;
  const int wave = tid >> 6, lane = tid & 63;
  const int wm = wave >> 1, wn = wave & 1;
  const int ar = tid >> 2, ak = (tid & 3) * 16;
  const int br = tid >> 1, bk = (tid & 1) * 32;

  f32x4 acc[2][4];
#pragma unroll
  for (int i = 0; i < 2; ++i)
#pragma unroll
    for (int j = 0; j < 4; ++j) acc[i][j] = {0.f, 0.f, 0.f, 0.f};

  const ushort_t* pa = outs + (size_t)(m0 + ar) * HH + ak;
  uint4 av0 = *(const uint4*)pa, av1 = *(const uint4*)(pa + 8);
  const ushort_t* pb = wlbf + (size_t)br * HH + bk;
  uint4 bv0 = *(const uint4*)pb, bv1 = *(const uint4*)(pb + 8);
  uint4 bv2 = *(const uint4*)(pb + 16), bv3 = *(const uint4*)(pb + 24);

  int buf = 0;
  for (int s = 0; s < 16; ++s) {
    *(uint4*)&Asl[buf][ar][ak] = av0;
    *(uint4*)&Asl[buf][ar][ak + 8] = av1;
    *(uint4*)&Bsl[buf][br][bk] = bv0;
    *(uint4*)&Bsl[buf][br][bk + 8] = bv1;
    *(uint4*)&Bsl[buf][br][bk + 16] = bv2;
    *(uint4*)&Bsl[buf][br][bk + 24] = bv3;
    if (s < 15) {
      int k0 = (s + 1) * 64;
      const ushort_t* qa = outs + (size_t)(m0 + ar) * HH + k0 + ak;
      av0 = *(const uint4*)qa; av1 = *(const uint4*)(qa + 8);
      const ushort_t* qb = wlbf + (size_t)br * HH + k0 + bk;
      bv0 = *(const uint4*)qb; bv1 = *(const uint4*)(qb + 8);
      bv2 = *(const uint4*)(qb + 16); bv3 = *(const uint4*)(qb + 24);
    }
    __syncthreads();
#pragma unroll
    for (int kk = 0; kk < 64; kk += 32) {
      int koff = kk + (lane >> 4) * 8;
      bf16x8 a0 = *(const bf16x8*)&Asl[buf][wm * 32 + (lane & 15)][koff];
      bf16x8 a1 = *(const bf16x8*)&Asl[buf][wm * 32 + 16 + (lane & 15)][koff];
      bf16x8 b0 = *(const bf16x8*)&Bsl[buf][wn * 64 + (lane & 15)][koff];
      bf16x8 b1 = *(const bf16x8*)&Bsl[buf][wn * 64 + 16 + (lane & 15)][koff];
      bf16x8 b2 = *(const bf16x8*)&Bsl[buf][wn * 64 + 32 + (lane & 15)][koff];
      bf16x8 b3 = *(const bf16x8*)&Bsl[buf][wn * 64 + 48 + (lane & 15)][koff];
      acc[0][0] = MFMA(a0, b0, acc[0][0]);
      acc[0][1] = MFMA(a0, b1, acc[0][1]);
      acc[0][2] = MFMA(a0, b2, acc[0][2]);
      acc[0][3] = MFMA(a0, b3, acc[0][3]);
      acc[1][0] = MFMA(a1, b0, acc[1][0]);
      acc[1][1] = MFMA(a1, b1, acc[1][1]);
      acc[1][2] = MFMA(a1, b2, acc[1][2]);
      acc[1][3] = MFMA(a1, b3, acc[1][3]);
    }
    buf ^= 1;
  }
#pragma unroll
  for (int i = 0; i < 2; ++i)
#pragma unroll
    for (int j = 0; j < 4; ++j)
#pragma unroll
      for (int r = 0; r < 4; ++r) {
        int m = m0 + wm * 32 + i * 16 + (lane >> 4) * 4 + r;
        int v = wn * 64 + j * 16 + (lane & 15);
        out[(size_t)m * VV + v] = acc[i][j][r] + bl[v];
      }
}

// ----------------------------------------------------------------------------
extern "C" void kernel_launch(void* const* d_in, const int* in_sizes, int n_in,
                              void* d_out, int out_size, void* d_ws, size_t ws_size,
                              hipStream_t stream) {
  const float* x    = (const float*)d_in[0];
  const float* h_in = (const float*)d_in[1];
  const float* c_in = (const float*)d_in[2];
  const float* Wx   = (const float*)d_in[3];
  const float* Wh   = (const float*)d_in[4];
  const float* bx   = (const float*)d_in[5];
  const float* bh   = (const float*)d_in[6];
  const float* Wl   = (const float*)d_in[7];
  const float* bl   = (const float*)d_in[8];

  char* ws = (char*)d_ws;
  size_t off = 0;
  ushort_t* wcombT = (ushort_t*)(ws + off); off += (size_t)NG * KK * 2;        // 9.4 MB
  ushort_t* outs   = (ushort_t*)(ws + off); off += (size_t)BB * TT * HH * 2;   // 67 MB
  ushort_t* hbf    = (ushort_t*)(ws + off); off += (size_t)2 * BB * HH * 2;    // ping-pong
  float*    bias   = (float*)(ws + off);    off += (size_t)NG * 4;
  ushort_t* wlbf   = (ushort_t*)(ws + off); off += (size_t)VV * HH * 2;
  off = (off + 127) & ~(size_t)127;
  unsigned* bar    = (unsigned*)(ws + off); off += 1056 * 4;

  float* out  = (float*)d_out;
  float* hout = out + (size_t)BB * TT * VV;
  float* cout = hout + (size_t)BB * HH;
  // xbf (8.4 MB) aliases the logits region of d_out (16.8 MB): read only by
  // lstm_persist, overwritten afterwards by logits_gemm. No ws growth.
  ushort_t* xbf = (ushort_t*)d_out;

  init_misc<<<dim3(512), dim3(256), 0, stream>>>(h_in, Wl, bx, bh,
                                                 hbf, wlbf, bias, bar);
  xconv<<<dim3(2048), dim3(256), 0, stream>>>(x, xbf);
  build_wcombT<<<dim3(36, 32, 4), dim3(256), 0, stream>>>(Wx, Wh, wcombT);

  {
    unsigned* outs32 = (unsigned*)outs;
    void* kargs[] = {(void*)&xbf, (void*)&wcombT, (void*)&bias, (void*)&hbf,
                     (void*)&outs32, (void*)&c_in, (void*)&hout, (void*)&cout,
                     (void*)&bar};
    hipError_t ce = hipLaunchCooperativeKernel((const void*)lstm_persist,
                                               dim3(256), dim3(256), kargs, 0,
                                               stream);
    if (ce != hipSuccess) {
      (void)hipGetLastError();  // clear sticky error; fall back to plain launch
      lstm_persist<<<dim3(256), dim3(256), 0, stream>>>(
          xbf, wcombT, bias, hbf, (unsigned*)outs, c_in, hout, cout, bar);
    }
  }

  logits_gemm<<<dim3(512), dim3(256), 0, stream>>>(outs, wlbf, bl, out);
}

// Round 8
// 1214.280 us; speedup vs baseline: 2.5083x; 1.4276x over previous
//
#include <hip/hip_runtime.h>
#include <hip/hip_bf16.h>

#define BB 128
#define TT 256
#define VV 128
#define HH 1024
#define NG 4096   // 4*H gate rows (permuted: n = hu*4 + gate)
#define KK 1152   // V + H fused reduction dim
#define TVV (TT * VV)

typedef unsigned short ushort_t;
typedef short bf16x8 __attribute__((ext_vector_type(8)));
typedef float f32x4 __attribute__((ext_vector_type(4)));

__device__ __forceinline__ ushort_t f2bf(float f) {
  unsigned u = __builtin_bit_cast(unsigned, f);
  u += 0x7fffu + ((u >> 16) & 1u);   // RTNE
  return (ushort_t)(u >> 16);
}

__device__ __forceinline__ uint4 pack8(const float* p) {
  float4 a = *(const float4*)p;
  float4 b = *(const float4*)(p + 4);
  uint4 r;
  r.x = (unsigned)f2bf(a.x) | ((unsigned)f2bf(a.y) << 16);
  r.y = (unsigned)f2bf(a.z) | ((unsigned)f2bf(a.w) << 16);
  r.z = (unsigned)f2bf(b.x) | ((unsigned)f2bf(b.y) << 16);
  r.w = (unsigned)f2bf(b.z) | ((unsigned)f2bf(b.w) << 16);
  return r;
}

__device__ __forceinline__ f32x4 MFMA(bf16x8 a, bf16x8 b, f32x4 c) {
  return __builtin_amdgcn_mfma_f32_16x16x32_bf16(a, b, c, 0, 0, 0);
}

__device__ __forceinline__ float fsig(float x) {
  return 1.f / (1.f + __expf(-x));
}

// L2-bypass coherent 16B load from LLC (sc0 sc1), immediate byte offset.
#define STG(dst, base, off)                                             \
  asm volatile("global_load_dwordx4 %0, %1, off offset:" off " sc0 sc1" \
               : "=&v"(dst) : "v"(base))
#define VWAIT(n)                                          \
  asm volatile("s_waitcnt vmcnt(" #n ")" ::: "memory");   \
  __builtin_amdgcn_sched_barrier(0)

// ---------------- init: h0 bf16, Wl->bf16, bias = bx+bh (permuted), tags ----
__global__ void init_misc(const float* __restrict__ h_in, const float* __restrict__ Wl,
                          const float* __restrict__ bx, const float* __restrict__ bh,
                          ushort_t* __restrict__ hbf0, ushort_t* __restrict__ wlbf,
                          float* __restrict__ bias, unsigned* __restrict__ bar) {
  int i = blockIdx.x * blockDim.x + threadIdx.x;   // grid covers 131072 exactly
  hbf0[i] = f2bf(h_in[i]);
  wlbf[i] = f2bf(Wl[i]);
  if (i < NG) {
    int kg = i & 3, hc = i >> 2;
    bias[i] = bx[kg * HH + hc] + bh[kg * HH + hc];
  }
  if (i < 1056) bar[i] = 0u;
}

// ---------------- x fp32 -> bf16 once (8 elems/thread) ----------------------
__global__ void xconv(const float* __restrict__ x, ushort_t* __restrict__ xbf) {
  size_t i = (size_t)(blockIdx.x * blockDim.x + threadIdx.x) * 8;
  *(uint4*)(xbf + i) = pack8(x + i);
}

// ------------- build WcombT[n][k] bf16, n = hu*4+kg, k = [x(128) | h(1024)] --
__global__ void build_wcombT(const float* __restrict__ Wx, const float* __restrict__ Wh,
                             ushort_t* __restrict__ wcombT) {
  __shared__ float tile[32][33];
  const int k0 = blockIdx.x * 32, hc0 = blockIdx.y * 32, kg = blockIdx.z;
  const int tid = threadIdx.x;
#pragma unroll
  for (int p = 0; p < 4; ++p) {
    int kk = (tid >> 5) + p * 8, hh = tid & 31;
    int k = k0 + kk, hc = hc0 + hh;
    float v = (k < VV) ? Wx[kg * VV * HH + k * HH + hc]
                       : Wh[kg * HH * HH + (k - VV) * HH + hc];
    tile[kk][hh] = v;
  }
  __syncthreads();
#pragma unroll
  for (int p = 0; p < 4; ++p) {
    int hh = (tid >> 5) + p * 8, kk = tid & 31;
    int n = (hc0 + hh) * 4 + kg;
    wcombT[n * KK + k0 + kk] = f2bf(tile[kk][hh]);
  }
}

// ---------------- persistent LSTM: transposed GEMM, LDS-staged h ------------
// grid 256: mb = blk&3 (32 batch), nb = blk>>2 (64 gate rows = 16 hu).
// Wave w owns gate rows 16w..16w+15 (A-operand, weights in 144 VGPR),
// N = 32 batch (2 MFMA tiles), full K. C: row=gate, col=batch -> the 4 gates
// of one hu land in one lane's acc[0..3] => shuffle-free pointwise.
__global__ __launch_bounds__(256, 1) void lstm_persist(
    const ushort_t* __restrict__ xbf, const ushort_t* __restrict__ wcombT,
    const float* __restrict__ bias, ushort_t* __restrict__ hping,
    unsigned* __restrict__ outs32, const float* __restrict__ c_in,
    float* __restrict__ hout, float* __restrict__ cout,
    unsigned* __restrict__ bar) {
  __shared__ __align__(16) ushort_t hs[32 * 1024];   // 64 KB h panel

  const int tid = threadIdx.x;
  const int mb = blockIdx.x & 3;
  const int b0 = mb * 32;
  const int nbk = blockIdx.x >> 2;                 // 0..63
  const int n0 = nbk * 64;
  const int wave = tid >> 6, lane = tid & 63;
  const int c15 = lane & 15, q = lane >> 4;
  const int hu = (n0 >> 2) + 4 * wave + q;         // this lane's h-unit
  const int bA = b0 + c15, bB = b0 + 16 + c15;     // batch cols (nb=0/1)

  // ---- one-time: weight A-fragments into registers (36 x 4 = 144 VGPR) ----
  bf16x8 wreg[36];
#pragma unroll
  for (int ks = 0; ks < 36; ++ks)
    wreg[ks] = *(const bf16x8*)(wcombT +
        (size_t)(n0 + 16 * wave + c15) * KK + ks * 32 + q * 8);

  const float4 biasv = *(const float4*)(bias + n0 + 16 * wave + 4 * q);
  float crA = c_in[(size_t)bA * HH + hu];
  float crB = c_in[(size_t)bB * HH + hu];

  // x B-fragment pointers (batch col = c15 / 16+c15)
  const ushort_t* xlA = xbf + (size_t)bA * TVV + q * 8;
  const ushort_t* xlB = xbf + (size_t)bB * TVV + q * 8;

  bf16x8 xrA[4], xrB[4];
#pragma unroll
  for (int i = 0; i < 4; ++i) {
    xrA[i] = *(const bf16x8*)(xlA + i * 32);
    xrB[i] = *(const bf16x8*)(xlB + i * 32);
  }

  // acc chains: accA = even slices, accB = odd slices; [nb]
  f32x4 accA[2], accB[2];
  accA[0] = MFMA(wreg[0], xrA[0], (f32x4){0.f,0.f,0.f,0.f});
  accA[1] = MFMA(wreg[0], xrB[0], (f32x4){0.f,0.f,0.f,0.f});
  accB[0] = MFMA(wreg[1], xrA[1], (f32x4){0.f,0.f,0.f,0.f});
  accB[1] = MFMA(wreg[1], xrB[1], (f32x4){0.f,0.f,0.f,0.f});
  accA[0] = MFMA(wreg[2], xrA[2], accA[0]);
  accA[1] = MFMA(wreg[2], xrB[2], accA[1]);
  accB[0] = MFMA(wreg[3], xrA[3], accB[0]);
  accB[1] = MFMA(wreg[3], xrB[3], accB[1]);

  // staging geometry: thread -> row = tid>>3, 16B chunk col = tid&7 (+8p)
  const int srow = tid >> 3, scol = tid & 7;
  const ushort_t* sb0 = hping + (size_t)(b0 + srow) * HH + scol * 8;
  const ushort_t* sb1 = sb0 + (size_t)BB * HH;
  const unsigned wb = (unsigned)srow * 2048u +
                      (((unsigned)scol * 16u) ^ (((unsigned)srow & 7u) << 4));
  // B-frag LDS addressing
  const unsigned rbase0 = (unsigned)(c15) * 2048u;
  const unsigned rbase1 = (unsigned)(16 + c15) * 2048u;
  const unsigned swzm = ((unsigned)c15 & 7u) << 4;
  const unsigned q16 = (unsigned)q * 16u;

  unsigned* tags = bar;                            // tags[mb*64 + nb]

  for (int t = 0; t < TT; ++t) {
    const ushort_t* sbase = (t & 1) ? sb1 : sb0;
    ushort_t* hn_ = hping + (size_t)((t + 1) & 1) * BB * HH;

    // ---- stage h -> LDS: issue all 16 bypass loads, two write phases ----
    uint4 s0,s1,s2,s3,s4,s5,s6,s7,s8,s9,s10,s11,s12,s13,s14,s15;
    __builtin_amdgcn_sched_barrier(0);
    STG(s0, sbase, "0");    STG(s1, sbase, "128");
    STG(s2, sbase, "256");  STG(s3, sbase, "384");
    STG(s4, sbase, "512");  STG(s5, sbase, "640");
    STG(s6, sbase, "768");  STG(s7, sbase, "896");
    STG(s8, sbase, "1024"); STG(s9, sbase, "1152");
    STG(s10, sbase, "1280"); STG(s11, sbase, "1408");
    STG(s12, sbase, "1536"); STG(s13, sbase, "1664");
    STG(s14, sbase, "1792"); STG(s15, sbase, "1920");
    VWAIT(8);                                      // half1 (s0..s7) ready
    *(uint4*)((char*)hs + wb) = s0;
    *(uint4*)((char*)hs + wb + 128) = s1;
    *(uint4*)((char*)hs + wb + 256) = s2;
    *(uint4*)((char*)hs + wb + 384) = s3;
    *(uint4*)((char*)hs + wb + 512) = s4;
    *(uint4*)((char*)hs + wb + 640) = s5;
    *(uint4*)((char*)hs + wb + 768) = s6;
    *(uint4*)((char*)hs + wb + 896) = s7;
    __syncthreads();                               // half1 visible

    // ---- MFMA h slices s=0..7 (k-cols 0..255) ----
#pragma unroll
    for (int s = 0; s < 8; ++s) {
      bf16x8 f0 = *(const bf16x8*)((const char*)hs +
                   (rbase0 + (((unsigned)s * 64u + q16) ^ swzm)));
      bf16x8 f1 = *(const bf16x8*)((const char*)hs +
                   (rbase1 + (((unsigned)s * 64u + q16) ^ swzm)));
      if (s & 1) { accB[0] = MFMA(wreg[4 + s], f0, accB[0]);
                   accB[1] = MFMA(wreg[4 + s], f1, accB[1]); }
      else       { accA[0] = MFMA(wreg[4 + s], f0, accA[0]);
                   accA[1] = MFMA(wreg[4 + s], f1, accA[1]); }
    }
    VWAIT(0);                                      // half2 (s8..s15) ready
    *(uint4*)((char*)hs + wb + 1024) = s8;
    *(uint4*)((char*)hs + wb + 1152) = s9;
    *(uint4*)((char*)hs + wb + 1280) = s10;
    *(uint4*)((char*)hs + wb + 1408) = s11;
    *(uint4*)((char*)hs + wb + 1536) = s12;
    *(uint4*)((char*)hs + wb + 1664) = s13;
    *(uint4*)((char*)hs + wb + 1792) = s14;
    *(uint4*)((char*)hs + wb + 1920) = s15;
    // ---- MFMA h slices s=8..15 while half2 writes land ----
#pragma unroll
    for (int s = 8; s < 16; ++s) {
      bf16x8 f0 = *(const bf16x8*)((const char*)hs +
                   (rbase0 + (((unsigned)s * 64u + q16) ^ swzm)));
      bf16x8 f1 = *(const bf16x8*)((const char*)hs +
                   (rbase1 + (((unsigned)s * 64u + q16) ^ swzm)));
      if (s & 1) { accB[0] = MFMA(wreg[4 + s], f0, accB[0]);
                   accB[1] = MFMA(wreg[4 + s], f1, accB[1]); }
      else       { accA[0] = MFMA(wreg[4 + s], f0, accA[0]);
                   accA[1] = MFMA(wreg[4 + s], f1, accA[1]); }
    }
    __syncthreads();                               // half2 visible
#pragma unroll
    for (int s = 16; s < 32; ++s) {
      bf16x8 f0 = *(const bf16x8*)((const char*)hs +
                   (rbase0 + (((unsigned)s * 64u + q16) ^ swzm)));
      bf16x8 f1 = *(const bf16x8*)((const char*)hs +
                   (rbase1 + (((unsigned)s * 64u + q16) ^ swzm)));
      if (s & 1) { accB[0] = MFMA(wreg[4 + s], f0, accB[0]);
                   accB[1] = MFMA(wreg[4 + s], f1, accB[1]); }
      else       { accA[0] = MFMA(wreg[4 + s], f0, accA[0]);
                   accA[1] = MFMA(wreg[4 + s], f1, accA[1]); }
    }

    // ---- pointwise: 4 gates of (hu, b) live in this lane's acc[0..3] ----
    const bool last = (t == TT - 1);
    unsigned hpk[2], opk[2];
#pragma unroll
    for (int nb = 0; nb < 2; ++nb) {
      f32x4 g = (nb ? accA[1] : accA[0]) + (nb ? accB[1] : accB[0]);
      float iv = fsig(g[0] + biasv.x);
      float fv = fsig(g[1] + biasv.y);
      float gv = 2.f * fsig(2.f * (g[2] + biasv.z)) - 1.f;
      float ov = fsig(g[3] + biasv.w);
      float cold = nb ? crB : crA;
      float cn = fv * cold + iv * gv;
      if (nb) crB = cn; else crA = cn;
      float hn = ov * (2.f * fsig(cn + cn) - 1.f);
      unsigned hb = f2bf(hn), ob = f2bf(ov);
      unsigned hbp = (unsigned)__shfl_xor((int)hb, 16);
      unsigned obp = (unsigned)__shfl_xor((int)ob, 16);
      hpk[nb] = hb | (hbp << 16);
      opk[nb] = ob | (obp << 16);
      if (last) {
        int b = nb ? bB : bA;
        hout[(size_t)b * HH + hu] = hn;
        cout[(size_t)b * HH + hu] = cn;
      }
    }
    // h stores first (they gate the tag), even-q lanes, dword WT
    if (!last && (q & 1) == 0) {
      __hip_atomic_store((unsigned*)(hn_ + (size_t)bA * HH + hu), hpk[0],
                         __ATOMIC_RELAXED, __HIP_MEMORY_SCOPE_AGENT);
      __hip_atomic_store((unsigned*)(hn_ + (size_t)bB * HH + hu), hpk[1],
                         __ATOMIC_RELAXED, __HIP_MEMORY_SCOPE_AGENT);
    }

    if (!last) {
      __syncthreads();   // vmcnt(0) in every wave: h-stores at LLC
      if (tid == 0)
        __hip_atomic_store(tags + mb * 64 + nbk, (unsigned)(t + 1),
                           __ATOMIC_RELAXED, __HIP_MEMORY_SCOPE_AGENT);
      // ---- poll shadow: outs stores, x prefetch, acc re-init + x MFMA ----
      if ((q & 1) == 0) {
        outs32[(((size_t)bA * TT + t) * HH + hu) >> 1] = opk[0];
        outs32[(((size_t)bB * TT + t) * HH + hu) >> 1] = opk[1];
      }
#pragma unroll
      for (int i = 0; i < 4; ++i) {
        xrA[i] = *(const bf16x8*)(xlA + (t + 1) * VV + i * 32);
        xrB[i] = *(const bf16x8*)(xlB + (t + 1) * VV + i * 32);
      }
      accA[0] = MFMA(wreg[0], xrA[0], (f32x4){0.f,0.f,0.f,0.f});
      accA[1] = MFMA(wreg[0], xrB[0], (f32x4){0.f,0.f,0.f,0.f});
      accB[0] = MFMA(wreg[1], xrA[1], (f32x4){0.f,0.f,0.f,0.f});
      accB[1] = MFMA(wreg[1], xrB[1], (f32x4){0.f,0.f,0.f,0.f});
      accA[0] = MFMA(wreg[2], xrA[2], accA[0]);
      accA[1] = MFMA(wreg[2], xrB[2], accA[1]);
      accB[0] = MFMA(wreg[3], xrA[3], accB[0]);
      accB[1] = MFMA(wreg[3], xrB[3], accB[1]);
      // one coalesced 64-tag poll (bypass loads), no RMW, no fence
      if (tid < 64) {
        const unsigned* tg = tags + mb * 64 + tid;
        unsigned tgt = (unsigned)(t + 1);
        while (true) {
          unsigned v = __hip_atomic_load(tg, __ATOMIC_RELAXED,
                                         __HIP_MEMORY_SCOPE_AGENT);
          if (__all(v >= tgt)) break;
          __builtin_amdgcn_s_sleep(1);
        }
      }
      __syncthreads();
      __builtin_amdgcn_sched_barrier(0);
    } else {
      if ((q & 1) == 0) {
        outs32[(((size_t)bA * TT + t) * HH + hu) >> 1] = opk[0];
        outs32[(((size_t)bB * TT + t) * HH + hu) >> 1] = opk[1];
      }
    }
  }
}

// ---------------- logits = outs(bf16) @ Wl^T + bl ---------------------------
// grid 512, 256 threads (waves 2x2), WG tile 64(M) x 128(N=V)
__global__ __launch_bounds__(256) void logits_gemm(
    const ushort_t* __restrict__ outs, const ushort_t* __restrict__ wlbf,
    const float* __restrict__ bl, float* __restrict__ out) {
  __shared__ __align__(16) ushort_t Asl[2][64][72];
  __shared__ __align__(16) ushort_t Bsl[2][128][72];
  const int tid = threadIdx.x;
  const int m0 = blockIdx.x * 64;
  const int wave = tid >> 6, lane = tid & 63;
  const int wm = wave >> 1, wn = wave & 1;
  const int ar = tid >> 2, ak = (tid & 3) * 16;
  const int br = tid >> 1, bk = (tid & 1) * 32;

  f32x4 acc[2][4];
#pragma unroll
  for (int i = 0; i < 2; ++i)
#pragma unroll
    for (int j = 0; j < 4; ++j) acc[i][j] = {0.f, 0.f, 0.f, 0.f};

  const ushort_t* pa = outs + (size_t)(m0 + ar) * HH + ak;
  uint4 av0 = *(const uint4*)pa, av1 = *(const uint4*)(pa + 8);
  const ushort_t* pb = wlbf + (size_t)br * HH + bk;
  uint4 bv0 = *(const uint4*)pb, bv1 = *(const uint4*)(pb + 8);
  uint4 bv2 = *(const uint4*)(pb + 16), bv3 = *(const uint4*)(pb + 24);

  int buf = 0;
  for (int s = 0; s < 16; ++s) {
    *(uint4*)&Asl[buf][ar][ak] = av0;
    *(uint4*)&Asl[buf][ar][ak + 8] = av1;
    *(uint4*)&Bsl[buf][br][bk] = bv0;
    *(uint4*)&Bsl[buf][br][bk + 8] = bv1;
    *(uint4*)&Bsl[buf][br][bk + 16] = bv2;
    *(uint4*)&Bsl[buf][br][bk + 24] = bv3;
    if (s < 15) {
      int k0 = (s + 1) * 64;
      const ushort_t* qa = outs + (size_t)(m0 + ar) * HH + k0 + ak;
      av0 = *(const uint4*)qa; av1 = *(const uint4*)(qa + 8);
      const ushort_t* qb = wlbf + (size_t)br * HH + k0 + bk;
      bv0 = *(const uint4*)qb; bv1 = *(const uint4*)(qb + 8);
      bv2 = *(const uint4*)(qb + 16); bv3 = *(const uint4*)(qb + 24);
    }
    __syncthreads();
#pragma unroll
    for (int kk = 0; kk < 64; kk += 32) {
      int koff = kk + (lane >> 4) * 8;
      bf16x8 a0 = *(const bf16x8*)&Asl[buf][wm * 32 + (lane & 15)][koff];
      bf16x8 a1 = *(const bf16x8*)&Asl[buf][wm * 32 + 16 + (lane & 15)][koff];
      bf16x8 b0 = *(const bf16x8*)&Bsl[buf][wn * 64 + (lane & 15)][koff];
      bf16x8 b1 = *(const bf16x8*)&Bsl[buf][wn * 64 + 16 + (lane & 15)][koff];
      bf16x8 b2 = *(const bf16x8*)&Bsl[buf][wn * 64 + 32 + (lane & 15)][koff];
      bf16x8 b3 = *(const bf16x8*)&Bsl[buf][wn * 64 + 48 + (lane & 15)][koff];
      acc[0][0] = MFMA(a0, b0, acc[0][0]);
      acc[0][1] = MFMA(a0, b1, acc[0][1]);
      acc[0][2] = MFMA(a0, b2, acc[0][2]);
      acc[0][3] = MFMA(a0, b3, acc[0][3]);
      acc[1][0] = MFMA(a1, b0, acc[1][0]);
      acc[1][1] = MFMA(a1, b1, acc[1][1]);
      acc[1][2] = MFMA(a1, b2, acc[1][2]);
      acc[1][3] = MFMA(a1, b3, acc[1][3]);
    }
    buf ^= 1;
  }
#pragma unroll
  for (int i = 0; i < 2; ++i)
#pragma unroll
    for (int j = 0; j < 4; ++j)
#pragma unroll
      for (int r = 0; r < 4; ++r) {
        int m = m0 + wm * 32 + i * 16 + (lane >> 4) * 4 + r;
        int v = wn * 64 + j * 16 + (lane & 15);
        out[(size_t)m * VV + v] = acc[i][j][r] + bl[v];
      }
}

// ----------------------------------------------------------------------------
extern "C" void kernel_launch(void* const* d_in, const int* in_sizes, int n_in,
                              void* d_out, int out_size, void* d_ws, size_t ws_size,
                              hipStream_t stream) {
  const float* x    = (const float*)d_in[0];
  const float* h_in = (const float*)d_in[1];
  const float* c_in = (const float*)d_in[2];
  const float* Wx   = (const float*)d_in[3];
  const float* Wh   = (const float*)d_in[4];
  const float* bx   = (const float*)d_in[5];
  const float* bh   = (const float*)d_in[6];
  const float* Wl   = (const float*)d_in[7];
  const float* bl   = (const float*)d_in[8];

  char* ws = (char*)d_ws;
  size_t off = 0;
  ushort_t* wcombT = (ushort_t*)(ws + off); off += (size_t)NG * KK * 2;        // 9.4 MB
  ushort_t* outs   = (ushort_t*)(ws + off); off += (size_t)BB * TT * HH * 2;   // 67 MB
  ushort_t* hbf    = (ushort_t*)(ws + off); off += (size_t)2 * BB * HH * 2;    // ping-pong
  float*    bias   = (float*)(ws + off);    off += (size_t)NG * 4;
  ushort_t* wlbf   = (ushort_t*)(ws + off); off += (size_t)VV * HH * 2;
  off = (off + 127) & ~(size_t)127;
  unsigned* bar    = (unsigned*)(ws + off); off += 1056 * 4;

  float* out  = (float*)d_out;
  float* hout = out + (size_t)BB * TT * VV;
  float* cout = hout + (size_t)BB * HH;
  // xbf (8.4 MB) aliases the logits region of d_out (16.8 MB): read only by
  // lstm_persist, overwritten afterwards by logits_gemm. No ws growth.
  ushort_t* xbf = (ushort_t*)d_out;

  init_misc<<<dim3(512), dim3(256), 0, stream>>>(h_in, Wl, bx, bh,
                                                 hbf, wlbf, bias, bar);
  xconv<<<dim3(2048), dim3(256), 0, stream>>>(x, xbf);
  build_wcombT<<<dim3(36, 32, 4), dim3(256), 0, stream>>>(Wx, Wh, wcombT);

  {
    unsigned* outs32 = (unsigned*)outs;
    void* kargs[] = {(void*)&xbf, (void*)&wcombT, (void*)&bias, (void*)&hbf,
                     (void*)&outs32, (void*)&c_in, (void*)&hout, (void*)&cout,
                     (void*)&bar};
    hipError_t ce = hipLaunchCooperativeKernel((const void*)lstm_persist,
                                               dim3(256), dim3(256), kargs, 0,
                                               stream);
    if (ce != hipSuccess) {
      (void)hipGetLastError();  // clear sticky error; fall back to plain launch
      lstm_persist<<<dim3(256), dim3(256), 0, stream>>>(
          xbf, wcombT, bias, hbf, (unsigned*)outs, c_in, hout, cout, bar);
    }
  }

  logits_gemm<<<dim3(512), dim3(256), 0, stream>>>(outs, wlbf, bl, out);
}